// Round 1
// baseline (1052.481 us; speedup 1.0000x reference)
//
#include <hip/hip_runtime.h>
#include <math.h>

typedef unsigned int u32;
typedef unsigned short u16;

#define NB 16
#define NS 128
#define NTW 16
#define NEDIM 300
#define NCED 50
#define NCH 50
#define NTAGS 10
#define XDIM 400
#define NWIN 1928

__device__ __forceinline__ float sigf(float x){ return 1.0f/(1.0f+expf(-x)); }
__device__ __forceinline__ u16 f2bu(float f){
  u32 u = __float_as_uint(f);
  return (u16)((u + 0x7fffu + ((u>>16)&1u))>>16);
}

// ---------------- embedding gather: x[:, 0:300] ----------------
__global__ void k_embed(const float* __restrict__ emb, const int* __restrict__ sent,
                        float* __restrict__ x){
  int n = blockIdx.x;                       // 0..2047 (b*128+s)
  int row = sent[n];
  const float* src = emb + (size_t)row*NEDIM;
  float* dst = x + (size_t)n*XDIM;
  for (int d = threadIdx.x; d < NEDIM; d += blockDim.x) dst[d] = src[d];
}

// ---------------- char BiLSTM (final hidden only) -> x[:, 300:400] ----------------
__global__ void k_char(const float* __restrict__ char_emb,
                       const float* __restrict__ wih_f, const float* __restrict__ whh_f, const float* __restrict__ b_f,
                       const float* __restrict__ wih_b, const float* __restrict__ whh_b, const float* __restrict__ b_b,
                       const int* __restrict__ wchars, const int* __restrict__ wlens,
                       const int* __restrict__ slens, float* __restrict__ x){
  const int dir = blockIdx.y;
  const int tid = threadIdx.x;
  __shared__ u16 wih_l[200*NCED];
  __shared__ u16 whh_l[200*NCED];
  __shared__ float z_l[200];
  __shared__ float h_l[NCH];
  const float* wih = dir ? wih_b : wih_f;
  const float* whh = dir ? whh_b : whh_f;
  const float* bp  = dir ? b_b   : b_f;
  for (int i = tid; i < 200*NCED; i += 256){
    wih_l[i] = f2bu(wih[i]);
    whh_l[i] = f2bu(whh[i]);
  }
  float bias = (tid < 200) ? bp[tid] : 0.f;
  __syncthreads();
  for (int w = 0; w < 4; ++w){
    int n = blockIdx.x*4 + w;
    int b = n >> 7, s = n & 127;
    int len = wlens[n];                    // in [1,16]
    float c = 0.f, hcur = 0.f;
    if (tid < NCH) h_l[tid] = 0.f;
    __syncthreads();
    for (int t = 0; t < len; ++t){
      int tt = dir ? (len-1-t) : t;
      int ch = wchars[n*NTW + tt];
      if (tid < 200){
        const float* xe = char_emb + ch*NCED;
        const u16* wr = wih_l + tid*NCED;
        const u16* ur = whh_l + tid*NCED;
        float acc = bias;
        #pragma unroll 10
        for (int k = 0; k < NCED; ++k){
          float wv = __uint_as_float(((u32)wr[k])<<16);
          float uv = __uint_as_float(((u32)ur[k])<<16);
          acc += wv*xe[k] + uv*h_l[k];
        }
        z_l[tid] = acc;
      }
      __syncthreads();
      if (tid < NCH){
        float gi = sigf(z_l[tid]);
        float gf = sigf(z_l[NCH+tid]);
        float gg = tanhf(z_l[2*NCH+tid]);
        float go = sigf(z_l[3*NCH+tid]);
        c = gf*c + gi*gg;
        hcur = go*tanhf(c);
        h_l[tid] = hcur;
      }
      __syncthreads();
    }
    if (tid < NCH){
      float v = (s < slens[b]) ? hcur : 0.f;   // pad_sequence zeroing
      x[(size_t)n*XDIM + NEDIM + dir*NCH + tid] = v;
    }
  }
}

// ---------------- pack word-LSTM whh into bf16-pair, k-major ----------------
// whhT2[dir][k2][j] = pack(bf16(whh[j][2k2+1]) , bf16(whh[j][2k2]))
__global__ void k_wprep(const float* __restrict__ whh_f, const float* __restrict__ whh_b,
                        u32* __restrict__ whhT2){
  int gid = blockIdx.x*256 + threadIdx.x;   // 0..262143
  int dir = gid >> 17;
  int rem = gid & 131071;
  int k2 = rem >> 10;
  int j  = rem & 1023;
  const float* src = dir ? whh_b : whh_f;
  u32 u0 = f2bu(src[j*256 + 2*k2]);
  u32 u1 = f2bu(src[j*256 + 2*k2 + 1]);
  whhT2[gid] = (u1<<16) | u0;
}

// ---------------- xg = x @ wih^T + b, both dirs (M=2048,N=2048,K=400) ----------------
__global__ void k_wxg(const float* __restrict__ x,
                      const float* __restrict__ wih_f, const float* __restrict__ wih_b,
                      const float* __restrict__ bw_f, const float* __restrict__ bw_b,
                      float* __restrict__ xg){
  __shared__ float As[16][65];
  __shared__ float Bs[16][65];
  int tid = threadIdx.x;
  int tx = tid & 15, ty = tid >> 4;
  int n0 = blockIdx.x * 64;        // output col (dir*1024 + j)
  int m0 = blockIdx.y * 64;        // row (b*128+s)
  int dir = n0 >> 10;
  int j0  = n0 & 1023;
  const float* wih = dir ? wih_b : wih_f;
  const float* bw  = dir ? bw_b  : bw_f;
  float acc[4][4] = {};
  for (int k0 = 0; k0 < 400; k0 += 16){
    #pragma unroll
    for (int i = 0; i < 4; ++i){
      int e = tid + i*256;
      int kk = e & 15, m = e >> 4;
      As[kk][m] = x[(m0+m)*XDIM + k0 + kk];
      Bs[kk][m] = wih[(j0+m)*XDIM + k0 + kk];
    }
    __syncthreads();
    #pragma unroll
    for (int kk = 0; kk < 16; ++kk){
      float av[4], bv[4];
      #pragma unroll
      for (int i=0;i<4;++i) av[i] = As[kk][ty*4+i];
      #pragma unroll
      for (int j=0;j<4;++j) bv[j] = Bs[kk][tx*4+j];
      #pragma unroll
      for (int i=0;i<4;++i)
        #pragma unroll
        for (int j=0;j<4;++j) acc[i][j] = fmaf(av[i], bv[j], acc[i][j]);
    }
    __syncthreads();
  }
  #pragma unroll
  for (int i=0;i<4;++i){
    int m = m0 + ty*4 + i;
    #pragma unroll
    for (int j=0;j<4;++j){
      int jj = j0 + tx*4 + j;
      xg[dir*2097152 + m*1024 + jj] = acc[i][j] + bw[jj];
    }
  }
}

// ---------------- word BiLSTM recurrence: 32 blocks = (b, dir), 512 thr ----------------
__global__ __launch_bounds__(512) void k_wlstm(const float* __restrict__ xg,
                        const u32* __restrict__ whhT2,
                        const int* __restrict__ slens, float* __restrict__ out){
  int b = blockIdx.x & 15, dir = blockIdx.x >> 4;
  int tid = threadIdx.x;
  int u = tid & 255, half = tid >> 8;
  __shared__ float h_l[256];
  __shared__ float part[1024];
  int len = slens[b];
  float c = 0.f;
  if (tid < 256) h_l[tid] = 0.f;
  __syncthreads();
  const float* xgb = xg + dir*2097152 + b*131072;
  const u32* W = whhT2 + dir*131072 + half*65536;   // this half's 64 k2-slices
  const float* hb = h_l + half*128;
  for (int t = 0; t < len; ++t){
    int row = dir ? (len-1-t) : t;
    const float* xr = xgb + row*1024;
    float a0=0.f,a1=0.f,a2=0.f,a3=0.f;
    #pragma unroll 4
    for (int k2 = 0; k2 < 64; ++k2){
      u32 w0 = W[k2*1024 + u];
      u32 w1 = W[k2*1024 + 256 + u];
      u32 w2 = W[k2*1024 + 512 + u];
      u32 w3 = W[k2*1024 + 768 + u];
      float h0 = hb[2*k2], h1 = hb[2*k2+1];
      a0 = fmaf(h0, __uint_as_float(w0<<16), fmaf(h1, __uint_as_float(w0 & 0xffff0000u), a0));
      a1 = fmaf(h0, __uint_as_float(w1<<16), fmaf(h1, __uint_as_float(w1 & 0xffff0000u), a1));
      a2 = fmaf(h0, __uint_as_float(w2<<16), fmaf(h1, __uint_as_float(w2 & 0xffff0000u), a2));
      a3 = fmaf(h0, __uint_as_float(w3<<16), fmaf(h1, __uint_as_float(w3 & 0xffff0000u), a3));
    }
    if (half){ part[u]=a0; part[256+u]=a1; part[512+u]=a2; part[768+u]=a3; }
    __syncthreads();
    if (!half){
      a0 += part[u]     + xr[u];
      a1 += part[256+u] + xr[256+u];
      a2 += part[512+u] + xr[512+u];
      a3 += part[768+u] + xr[768+u];
      float gi=sigf(a0), gf=sigf(a1), gg=tanhf(a2), go=sigf(a3);
      c = gf*c + gi*gg;
      float hn = go*tanhf(c);
      h_l[u] = hn;
      out[(b*128+row)*512 + dir*256 + u] = hn;
    }
    __syncthreads();
  }
}

// ---------------- prefix sums over s ----------------
__global__ void k_csum(const float* __restrict__ out, float* __restrict__ csum){
  int gid = blockIdx.x*256 + threadIdx.x;   // 8192 = 16*512
  int b = gid >> 9, d = gid & 511;
  float run = 0.f;
  csum[(b*129)*512 + d] = 0.f;
  for (int s = 0; s < 128; ++s){
    run += out[((b<<7)+s)*512 + d];
    csum[(b*129 + s + 1)*512 + d] = run;
  }
}

// ---------------- per-position first/last classifier terms ----------------
__global__ void k_ac(const float* __restrict__ out, const float* __restrict__ clf_w,
                     float* __restrict__ A, float* __restrict__ Cm){
  int gid = blockIdx.x*256 + threadIdx.x;   // 20480 = 2048*10
  int bs = gid / 10, tag = gid % 10;
  const float* o  = out + bs*512;
  const float* w1 = clf_w + tag*1536;       // "first" block
  const float* w3 = w1 + 1024;              // "last" block
  float a=0.f, cc=0.f;
  for (int d = 0; d < 512; ++d){
    float v = fmaxf(o[d], 0.f);
    a  = fmaf(v, w1[d], a);
    cc = fmaf(v, w3[d], cc);
  }
  A[gid] = a; Cm[gid] = cc;
}

// ---------------- window classifier: wave per (n,b) ----------------
__global__ void k_clf(const float* __restrict__ csum, const float* __restrict__ clf_w,
                      const float* __restrict__ clf_b, const float* __restrict__ A,
                      const float* __restrict__ Cm, float* __restrict__ dout){
  __shared__ float w2_l[NTAGS*512];
  int tid = threadIdx.x;
  for (int i = tid; i < NTAGS*512; i += 256){
    int tag = i >> 9, d = i & 511;
    w2_l[i] = clf_w[tag*1536 + 512 + d];    // "mean" block
  }
  __syncthreads();
  int q = blockIdx.x*4 + (tid >> 6);        // 0..30847
  int lane = tid & 63;
  int n = q >> 4, b = q & 15;
  // decode n -> (window size r, start s0)
  int rem = n, r = 1;
  while (rem >= 129 - r){ rem -= 129 - r; ++r; }
  int s0 = rem, s1 = s0 + r - 1;
  float invr = 1.0f / (float)r;
  int d0 = lane*8;
  const float* c0 = csum + (b*129 + s0    )*512 + d0;
  const float* c1 = csum + (b*129 + s0 + r)*512 + d0;
  float m[8];
  #pragma unroll
  for (int i=0;i<8;++i) m[i] = fmaxf((c1[i]-c0[i])*invr, 0.f);
  float p[10];
  #pragma unroll
  for (int tag=0; tag<NTAGS; ++tag){
    const float* w = w2_l + tag*512 + d0;
    float s = 0.f;
    #pragma unroll
    for (int i=0;i<8;++i) s = fmaf(m[i], w[i], s);
    #pragma unroll
    for (int off=32; off>=1; off>>=1) s += __shfl_xor(s, off);
    p[tag] = s;
  }
  if (lane == 0){
    #pragma unroll
    for (int tag=0; tag<NTAGS; ++tag){
      float v = p[tag] + A[(b*128+s0)*10+tag] + Cm[(b*128+s1)*10+tag] + clf_b[tag];
      dout[b*(NTAGS*NWIN) + tag*NWIN + n] = v;
    }
  }
}

extern "C" void kernel_launch(void* const* d_in, const int* in_sizes, int n_in,
                              void* d_out, int out_size, void* d_ws, size_t ws_size,
                              hipStream_t stream){
  (void)in_sizes; (void)n_in; (void)out_size; (void)ws_size;
  const float* emb      = (const float*)d_in[0];
  const float* char_emb = (const float*)d_in[1];
  const float* c_wih_f  = (const float*)d_in[2];
  const float* c_whh_f  = (const float*)d_in[3];
  const float* c_b_f    = (const float*)d_in[4];
  const float* c_wih_b  = (const float*)d_in[5];
  const float* c_whh_b  = (const float*)d_in[6];
  const float* c_b_b    = (const float*)d_in[7];
  const float* w_wih_f  = (const float*)d_in[8];
  const float* w_whh_f  = (const float*)d_in[9];
  const float* w_b_f    = (const float*)d_in[10];
  const float* w_wih_b  = (const float*)d_in[11];
  const float* w_whh_b  = (const float*)d_in[12];
  const float* w_b_b    = (const float*)d_in[13];
  const float* clf_w    = (const float*)d_in[14];
  const float* clf_b    = (const float*)d_in[15];
  const int* sentences  = (const int*)d_in[16];
  const int* slens      = (const int*)d_in[17];
  const int* wchars     = (const int*)d_in[18];
  const int* wlens      = (const int*)d_in[19];

  float* ws   = (float*)d_ws;
  float* x    = ws;                       // 2048*400      = 819,200
  float* xg   = ws + 819200;              // 2*2048*1024   = 4,194,304
  float* outb = ws + 5013504;             // 2048*512      = 1,048,576
  float* csum = ws + 6062080;             // 16*129*512    = 1,056,768
  float* A    = ws + 7118848;             // 2048*10
  float* Cm   = ws + 7139328;             // 2048*10
  u32*  whhT2 = (u32*)(ws + 7159808);     // 2*128*1024 uints

  hipMemsetAsync(outb, 0, (size_t)2048*512*sizeof(float), stream);
  k_embed<<<2048, 256, 0, stream>>>(emb, sentences, x);
  k_char<<<dim3(512,2), 256, 0, stream>>>(char_emb, c_wih_f, c_whh_f, c_b_f,
                                          c_wih_b, c_whh_b, c_b_b,
                                          wchars, wlens, slens, x);
  k_wprep<<<1024, 256, 0, stream>>>(w_whh_f, w_whh_b, whhT2);
  k_wxg<<<dim3(32,32), 256, 0, stream>>>(x, w_wih_f, w_wih_b, w_b_f, w_b_b, xg);
  k_wlstm<<<32, 512, 0, stream>>>(xg, whhT2, slens, outb);
  k_csum<<<32, 256, 0, stream>>>(outb, csum);
  k_ac<<<80, 256, 0, stream>>>(outb, clf_w, A, Cm);
  k_clf<<<7712, 256, 0, stream>>>(csum, clf_w, clf_b, A, Cm, (float*)d_out);
}

// Round 2
// 899.320 us; speedup vs baseline: 1.1703x; 1.1703x over previous
//
#include <hip/hip_runtime.h>
#include <math.h>

typedef unsigned int u32;
typedef unsigned short u16;
typedef __attribute__((ext_vector_type(8))) short short8;
typedef __attribute__((ext_vector_type(4))) float f32x4;
typedef __attribute__((ext_vector_type(4))) u32 u32x4;

#define NB 16
#define NS 128
#define NTW 16
#define NEDIM 300
#define NCED 50
#define NCH 50
#define NTAGS 10
#define XDIM 400
#define NWIN 1928

__device__ __forceinline__ float sigf(float x){ return 1.0f/(1.0f+__expf(-x)); }
__device__ __forceinline__ float tanhfast(float x){
  float e = __expf(2.0f*x);
  return 1.0f - 2.0f/(e + 1.0f);
}
__device__ __forceinline__ u16 f2bu(float f){
  u32 u = __float_as_uint(f);
  return (u16)((u + 0x7fffu + ((u>>16)&1u))>>16);
}
__device__ __forceinline__ float bf2f(u16 x){ return __uint_as_float(((u32)x)<<16); }

// ---------------- embedding gather: x[:, 0:300] ----------------
__global__ void k_embed(const float* __restrict__ emb, const int* __restrict__ sent,
                        float* __restrict__ x){
  int n = blockIdx.x;                       // 0..2047 (b*128+s)
  int row = sent[n];
  const float* src = emb + (size_t)row*NEDIM;
  float* dst = x + (size_t)n*XDIM;
  for (int d = threadIdx.x; d < NEDIM; d += blockDim.x) dst[d] = src[d];
}

// ---------------- char BiLSTM (final hidden only) -> x[:, 300:400] ----------------
__global__ void k_char(const float* __restrict__ char_emb,
                       const float* __restrict__ wih_f, const float* __restrict__ whh_f, const float* __restrict__ b_f,
                       const float* __restrict__ wih_b, const float* __restrict__ whh_b, const float* __restrict__ b_b,
                       const int* __restrict__ wchars, const int* __restrict__ wlens,
                       const int* __restrict__ slens, float* __restrict__ x){
  const int dir = blockIdx.y;
  const int tid = threadIdx.x;
  __shared__ u16 wih_l[200*NCED];
  __shared__ u16 whh_l[200*NCED];
  __shared__ float z_l[200];
  __shared__ float h_l[NCH];
  const float* wih = dir ? wih_b : wih_f;
  const float* whh = dir ? whh_b : whh_f;
  const float* bp  = dir ? b_b   : b_f;
  for (int i = tid; i < 200*NCED; i += 256){
    wih_l[i] = f2bu(wih[i]);
    whh_l[i] = f2bu(whh[i]);
  }
  float bias = (tid < 200) ? bp[tid] : 0.f;
  __syncthreads();
  for (int w = 0; w < 4; ++w){
    int n = blockIdx.x*4 + w;
    int b = n >> 7, s = n & 127;
    int len = wlens[n];                    // in [1,16]
    float c = 0.f, hcur = 0.f;
    if (tid < NCH) h_l[tid] = 0.f;
    __syncthreads();
    for (int t = 0; t < len; ++t){
      int tt = dir ? (len-1-t) : t;
      int ch = wchars[n*NTW + tt];
      if (tid < 200){
        const float* xe = char_emb + ch*NCED;
        const u16* wr = wih_l + tid*NCED;
        const u16* ur = whh_l + tid*NCED;
        float acc = bias;
        #pragma unroll 10
        for (int k = 0; k < NCED; ++k){
          float wv = __uint_as_float(((u32)wr[k])<<16);
          float uv = __uint_as_float(((u32)ur[k])<<16);
          acc += wv*xe[k] + uv*h_l[k];
        }
        z_l[tid] = acc;
      }
      __syncthreads();
      if (tid < NCH){
        float gi = sigf(z_l[tid]);
        float gf = sigf(z_l[NCH+tid]);
        float gg = tanhf(z_l[2*NCH+tid]);
        float go = sigf(z_l[3*NCH+tid]);
        c = gf*c + gi*gg;
        hcur = go*tanhf(c);
        h_l[tid] = hcur;
      }
      __syncthreads();
    }
    if (tid < NCH){
      float v = (s < slens[b]) ? hcur : 0.f;   // pad_sequence zeroing
      x[(size_t)n*XDIM + NEDIM + dir*NCH + tid] = v;
    }
  }
}

// ---------------- xg = bf16(x @ wih^T + b), both dirs (M=2048,N=2048,K=400) ----------------
__global__ void k_wxg(const float* __restrict__ x,
                      const float* __restrict__ wih_f, const float* __restrict__ wih_b,
                      const float* __restrict__ bw_f, const float* __restrict__ bw_b,
                      u16* __restrict__ xgb){
  __shared__ float As[16][65];
  __shared__ float Bs[16][65];
  int tid = threadIdx.x;
  int tx = tid & 15, ty = tid >> 4;
  int n0 = blockIdx.x * 64;        // output col (dir*1024 + j)
  int m0 = blockIdx.y * 64;        // row (b*128+s)
  int dir = n0 >> 10;
  int j0  = n0 & 1023;
  const float* wih = dir ? wih_b : wih_f;
  const float* bw  = dir ? bw_b  : bw_f;
  float acc[4][4] = {};
  for (int k0 = 0; k0 < 400; k0 += 16){
    #pragma unroll
    for (int i = 0; i < 4; ++i){
      int e = tid + i*256;
      int kk = e & 15, m = e >> 4;
      As[kk][m] = x[(m0+m)*XDIM + k0 + kk];
      Bs[kk][m] = wih[(j0+m)*XDIM + k0 + kk];
    }
    __syncthreads();
    #pragma unroll
    for (int kk = 0; kk < 16; ++kk){
      float av[4], bv[4];
      #pragma unroll
      for (int i=0;i<4;++i) av[i] = As[kk][ty*4+i];
      #pragma unroll
      for (int j=0;j<4;++j) bv[j] = Bs[kk][tx*4+j];
      #pragma unroll
      for (int i=0;i<4;++i)
        #pragma unroll
        for (int j=0;j<4;++j) acc[i][j] = fmaf(av[i], bv[j], acc[i][j]);
    }
    __syncthreads();
  }
  #pragma unroll
  for (int i=0;i<4;++i){
    int m = m0 + ty*4 + i;
    #pragma unroll
    for (int j=0;j<4;++j){
      int jj = j0 + tx*4 + j;
      xgb[(size_t)dir*2097152 + m*1024 + jj] = f2bu(acc[i][j] + bw[jj]);
    }
  }
}

// ---------------- word BiLSTM recurrence: 4 blocks = (dir, u-half), MFMA ----------------
// Weights register-resident as B-fragments. Cross-block h-half exchange per step
// via agent-scope atomics (double-buffered) + release/acquire flag.
__global__ __launch_bounds__(1024, 4) void k_wlstm2(
    const float* __restrict__ whh_f, const float* __restrict__ whh_b,
    const u16* __restrict__ xgB, const int* __restrict__ slens,
    float* __restrict__ out, u32* __restrict__ xh, int* __restrict__ flags){
  const int dir  = blockIdx.x >> 1;
  const int half = blockIdx.x & 1;
  const int tid  = threadIdx.x;
  const int lane = tid & 63;
  const int w    = tid >> 6;        // wave 0..15
  const int q    = lane >> 4;       // 0..3
  const int jc   = lane & 15;

  __shared__ __align__(16) u16  Hbuf[2][16*256];   // [buf][b][u]  bf16, swizzled rows
  __shared__ __align__(16) float abuf[32][64][4];  // [jt_local][lane][reg]
  __shared__ __align__(16) u16  xstg[2][16*512];   // [buf][b][gate][128 u-local] bf16

  const float* whh = dir ? whh_b : whh_f;

  // combine-role constants: wave handles u-tile v, batch regs {2*rsel, 2*rsel+1}
  const int v = w & 7, rsel = w >> 3;
  const int b0c = q*4 + 2*rsel, b1c = b0c + 1;
  const int len0 = slens[b0c], len1 = slens[b1c];
  // stage-role: this thread stages b=w, gate=q, 8 elems at jc*8
  const int len_s = slens[w];

  // ---- load B fragments (reg-resident weights) ----
  short8 Bf[2][8];
  #pragma unroll
  for (int l = 0; l < 2; ++l){
    int jt = w*2 + l;                       // 0..31
    int g = jt >> 3, vv = jt & 7;
    int j = g*256 + half*128 + vv*16 + jc;
    const float* wr = whh + (size_t)j*256;
    #pragma unroll
    for (int kc = 0; kc < 8; ++kc){
      int k0 = kc*32 + q*8;
      f32x4 w0 = *(const f32x4*)(wr + k0);
      f32x4 w1 = *(const f32x4*)(wr + k0 + 4);
      short8 s;
      s[0]=(short)f2bu(w0[0]); s[1]=(short)f2bu(w0[1]);
      s[2]=(short)f2bu(w0[2]); s[3]=(short)f2bu(w0[3]);
      s[4]=(short)f2bu(w1[0]); s[5]=(short)f2bu(w1[1]);
      s[6]=(short)f2bu(w1[2]); s[7]=(short)f2bu(w1[3]);
      Bf[l][kc] = s;
    }
  }

  // zero H state buffer 0
  for (int i = tid; i < 2048; i += 1024) ((u32*)Hbuf[0])[i] = 0u;

  // stage xg for t=0
  {
    int rowS = dir ? (len_s - 1) : 0;
    const u16* src = xgB + ((size_t)dir<<21) + ((w*128 + rowS)*1024 + q*256 + half*128 + jc*8);
    u32x4 d = *(const u32x4*)src;
    *(u32x4*)&xstg[0][(w*4 + q)*128 + jc*8] = d;
  }
  __syncthreads();

  const int fl_idx = dir*2 + half;
  const int fl_p   = dir*2 + (1 - half);
  u32* xh_own = xh + fl_idx*2048;
  u32* xh_par = xh + fl_p*2048;

  float c0 = 0.f, c1 = 0.f, h0 = 0.f, h1 = 0.f;
  int cur = 0;

  for (int t = 0; t < 128; ++t){
    // ---- stage loads for t+1 (written to LDS at end of step) ----
    u32x4 stg;
    const bool do_stage = (t < 127);
    if (do_stage){
      int rowS = dir ? (len_s - 2 - t) : (t + 1);
      rowS = rowS < 0 ? 0 : rowS;
      const u16* src = xgB + ((size_t)dir<<21) + ((w*128 + rowS)*1024 + q*256 + half*128 + jc*8);
      stg = *(const u32x4*)src;
    }

    // ---- MFMA: a = H @ W^T for this block's 32 j-tiles ----
    f32x4 acc0 = {0.f,0.f,0.f,0.f};
    f32x4 acc1 = {0.f,0.f,0.f,0.f};
    {
      const char* Hc = (const char*)Hbuf[cur];
      int arow = jc;                                 // A row m = lane&15 = batch
      #pragma unroll
      for (int kc = 0; kc < 8; ++kc){
        int kb = (kc*64 + q*16) ^ ((arow & 7) << 4); // byte offset in row (swizzled)
        short8 af = *(const short8*)(Hc + arow*512 + kb);
        acc0 = __builtin_amdgcn_mfma_f32_16x16x32_bf16(af, Bf[0][kc], acc0, 0, 0, 0);
        acc1 = __builtin_amdgcn_mfma_f32_16x16x32_bf16(af, Bf[1][kc], acc1, 0, 0, 0);
      }
    }
    *(f32x4*)&abuf[w*2  ][lane][0] = acc0;
    *(f32x4*)&abuf[w*2+1][lane][0] = acc1;
    __syncthreads();                                   // A: abuf ready

    // ---- gate combine: u-tile v, regs {2rsel, 2rsel+1} ----
    int nxt = cur ^ 1;
    {
      f32x4 zi = *(const f32x4*)&abuf[0*8+v][lane][0];
      f32x4 zf = *(const f32x4*)&abuf[1*8+v][lane][0];
      f32x4 zg = *(const f32x4*)&abuf[2*8+v][lane][0];
      f32x4 zo = *(const f32x4*)&abuf[3*8+v][lane][0];
      const u16* xs = xstg[t & 1];
      const int ucol = v*16 + jc;                      // u-local 0..127
      const int ug   = half*128 + ucol;                // global u

      float Zi0 = (rsel ? zi[2] : zi[0]) + bf2f(xs[(b0c*4+0)*128 + ucol]);
      float Zf0 = (rsel ? zf[2] : zf[0]) + bf2f(xs[(b0c*4+1)*128 + ucol]);
      float Zg0 = (rsel ? zg[2] : zg[0]) + bf2f(xs[(b0c*4+2)*128 + ucol]);
      float Zo0 = (rsel ? zo[2] : zo[0]) + bf2f(xs[(b0c*4+3)*128 + ucol]);
      if (t < len0){
        float gi = sigf(Zi0), gf = sigf(Zf0), gg = tanhfast(Zg0), go = sigf(Zo0);
        c0 = gf*c0 + gi*gg;
        h0 = go*tanhfast(c0);
        int row = dir ? (len0-1-t) : t;
        out[((b0c<<7)+row)*512 + dir*256 + ug] = h0;
      }
      float Zi1 = (rsel ? zi[3] : zi[1]) + bf2f(xs[(b1c*4+0)*128 + ucol]);
      float Zf1 = (rsel ? zf[3] : zf[1]) + bf2f(xs[(b1c*4+1)*128 + ucol]);
      float Zg1 = (rsel ? zg[3] : zg[1]) + bf2f(xs[(b1c*4+2)*128 + ucol]);
      float Zo1 = (rsel ? zo[3] : zo[1]) + bf2f(xs[(b1c*4+3)*128 + ucol]);
      if (t < len1){
        float gi = sigf(Zi1), gf = sigf(Zf1), gg = tanhfast(Zg1), go = sigf(Zo1);
        c1 = gf*c1 + gi*gg;
        h1 = go*tanhfast(c1);
        int row = dir ? (len1-1-t) : t;
        out[((b1c<<7)+row)*512 + dir*256 + ug] = h1;
      }
      // own-half H for next step (LDS, swizzled)
      u16 hb0 = f2bu(h0), hb1 = f2bu(h1);
      Hbuf[nxt][b0c*256 + ((((ug*2) ^ ((b0c&7)<<4))) >> 1)] = hb0;
      Hbuf[nxt][b1c*256 + ((((ug*2) ^ ((b1c&7)<<4))) >> 1)] = hb1;
      // publish to partner (packed pair), double-buffered by step parity
      u32 pack = ((u32)hb1 << 16) | (u32)hb0;
      __hip_atomic_store(&xh_own[(t&1)*1024 + ucol*8 + q*2 + rsel], pack,
                         __ATOMIC_RELAXED, __HIP_MEMORY_SCOPE_AGENT);
    }
    __syncthreads();                                   // B: stores issued+drained

    if (tid == 0){
      __hip_atomic_store(&flags[fl_idx], t+1, __ATOMIC_RELEASE, __HIP_MEMORY_SCOPE_AGENT);
      int spins = 0;
      while (__hip_atomic_load(&flags[fl_p], __ATOMIC_ACQUIRE, __HIP_MEMORY_SCOPE_AGENT) < t+1){
        __builtin_amdgcn_s_sleep(2);
        if (++spins > (1<<16)) break;                  // hang guard
      }
    }
    __syncthreads();                                   // S: partner data visible

    // ---- exchange-in: 1024 u32 -> partner half of Hbuf[nxt] ----
    {
      u32 d = __hip_atomic_load(&xh_par[(t&1)*1024 + tid],
                                __ATOMIC_RELAXED, __HIP_MEMORY_SCOPE_AGENT);
      int ul  = tid >> 3;
      int qq  = (tid >> 1) & 3, rs = tid & 1;
      int bb0 = qq*4 + rs*2, bb1 = bb0 + 1;
      int ugp = (1-half)*128 + ul;
      Hbuf[nxt][bb0*256 + ((((ugp*2) ^ ((bb0&7)<<4))) >> 1)] = (u16)(d & 0xffffu);
      Hbuf[nxt][bb1*256 + ((((ugp*2) ^ ((bb1&7)<<4))) >> 1)] = (u16)(d >> 16);
    }
    if (do_stage){
      *(u32x4*)&xstg[(t+1)&1][(w*4 + q)*128 + jc*8] = stg;
    }
    __syncthreads();                                   // C: Hbuf[nxt] complete
    cur = nxt;
  }
}

// ---------------- prefix sums over s ----------------
__global__ void k_csum(const float* __restrict__ out, float* __restrict__ csum){
  int gid = blockIdx.x*256 + threadIdx.x;   // 8192 = 16*512
  int b = gid >> 9, d = gid & 511;
  float run = 0.f;
  csum[(b*129)*512 + d] = 0.f;
  for (int s = 0; s < 128; ++s){
    run += out[((b<<7)+s)*512 + d];
    csum[(b*129 + s + 1)*512 + d] = run;
  }
}

// ---------------- per-position first/last classifier terms ----------------
__global__ void k_ac(const float* __restrict__ out, const float* __restrict__ clf_w,
                     float* __restrict__ A, float* __restrict__ Cm){
  int gid = blockIdx.x*256 + threadIdx.x;   // 20480 = 2048*10
  int bs = gid / 10, tag = gid % 10;
  const float* o  = out + bs*512;
  const float* w1 = clf_w + tag*1536;       // "first" block
  const float* w3 = w1 + 1024;              // "last" block
  float a=0.f, cc=0.f;
  for (int d = 0; d < 512; ++d){
    float vv = fmaxf(o[d], 0.f);
    a  = fmaf(vv, w1[d], a);
    cc = fmaf(vv, w3[d], cc);
  }
  A[gid] = a; Cm[gid] = cc;
}

// ---------------- window classifier: wave per (n,b) ----------------
__global__ void k_clf(const float* __restrict__ csum, const float* __restrict__ clf_w,
                      const float* __restrict__ clf_b, const float* __restrict__ A,
                      const float* __restrict__ Cm, float* __restrict__ dout){
  __shared__ float w2_l[NTAGS*512];
  int tid = threadIdx.x;
  for (int i = tid; i < NTAGS*512; i += 256){
    int tag = i >> 9, d = i & 511;
    w2_l[i] = clf_w[tag*1536 + 512 + d];    // "mean" block
  }
  __syncthreads();
  int qq = blockIdx.x*4 + (tid >> 6);       // 0..30847
  int lane = tid & 63;
  int n = qq >> 4, b = qq & 15;
  int rem = n, r = 1;
  while (rem >= 129 - r){ rem -= 129 - r; ++r; }
  int s0 = rem, s1 = s0 + r - 1;
  float invr = 1.0f / (float)r;
  int d0 = lane*8;
  const float* c0 = csum + (b*129 + s0    )*512 + d0;
  const float* c1 = csum + (b*129 + s0 + r)*512 + d0;
  float m[8];
  #pragma unroll
  for (int i=0;i<8;++i) m[i] = fmaxf((c1[i]-c0[i])*invr, 0.f);
  float p[10];
  #pragma unroll
  for (int tag=0; tag<NTAGS; ++tag){
    const float* wv = w2_l + tag*512 + d0;
    float s = 0.f;
    #pragma unroll
    for (int i=0;i<8;++i) s = fmaf(m[i], wv[i], s);
    #pragma unroll
    for (int off=32; off>=1; off>>=1) s += __shfl_xor(s, off);
    p[tag] = s;
  }
  if (lane == 0){
    #pragma unroll
    for (int tag=0; tag<NTAGS; ++tag){
      float vv = p[tag] + A[(b*128+s0)*10+tag] + Cm[(b*128+s1)*10+tag] + clf_b[tag];
      dout[b*(NTAGS*NWIN) + tag*NWIN + n] = vv;
    }
  }
}

extern "C" void kernel_launch(void* const* d_in, const int* in_sizes, int n_in,
                              void* d_out, int out_size, void* d_ws, size_t ws_size,
                              hipStream_t stream){
  (void)in_sizes; (void)n_in; (void)out_size; (void)ws_size;
  const float* emb      = (const float*)d_in[0];
  const float* char_emb = (const float*)d_in[1];
  const float* c_wih_f  = (const float*)d_in[2];
  const float* c_whh_f  = (const float*)d_in[3];
  const float* c_b_f    = (const float*)d_in[4];
  const float* c_wih_b  = (const float*)d_in[5];
  const float* c_whh_b  = (const float*)d_in[6];
  const float* c_b_b    = (const float*)d_in[7];
  const float* w_wih_f  = (const float*)d_in[8];
  const float* w_whh_f  = (const float*)d_in[9];
  const float* w_b_f    = (const float*)d_in[10];
  const float* w_wih_b  = (const float*)d_in[11];
  const float* w_whh_b  = (const float*)d_in[12];
  const float* w_b_b    = (const float*)d_in[13];
  const float* clf_w    = (const float*)d_in[14];
  const float* clf_b    = (const float*)d_in[15];
  const int* sentences  = (const int*)d_in[16];
  const int* slens      = (const int*)d_in[17];
  const int* wchars     = (const int*)d_in[18];
  const int* wlens      = (const int*)d_in[19];

  float* ws   = (float*)d_ws;
  float* x    = ws;                       // 819,200 f
  u16*  xgb   = (u16*)(ws + 819200);      // 4,194,304 u16 = 2,097,152 f
  float* outb = ws + 2916352;             // 1,048,576 f
  float* csum = ws + 3964928;             // 1,056,768 f
  float* A    = ws + 5021696;             // 20,480 f
  float* Cm   = ws + 5042176;             // 20,480 f
  u32*  xh    = (u32*)(ws + 5062656);     // 4 regions * 2048 u32 = 8192
  int*  flags = (int*)(ws + 5070848);     // 4 ints

  hipMemsetAsync(outb, 0, (size_t)2048*512*sizeof(float), stream);
  hipMemsetAsync(flags, 0, 256, stream);
  k_embed<<<2048, 256, 0, stream>>>(emb, sentences, x);
  k_char<<<dim3(512,2), 256, 0, stream>>>(char_emb, c_wih_f, c_whh_f, c_b_f,
                                          c_wih_b, c_whh_b, c_b_b,
                                          wchars, wlens, slens, x);
  k_wxg<<<dim3(32,32), 256, 0, stream>>>(x, w_wih_f, w_wih_b, w_b_f, w_b_b, xgb);
  k_wlstm2<<<4, 1024, 0, stream>>>(w_whh_f, w_whh_b, xgb, slens, outb, xh, flags);
  k_csum<<<32, 256, 0, stream>>>(outb, csum);
  k_ac<<<80, 256, 0, stream>>>(outb, clf_w, A, Cm);
  k_clf<<<7712, 256, 0, stream>>>(csum, clf_w, clf_b, A, Cm, (float*)d_out);
}